// Round 2
// baseline (1129.630 us; speedup 1.0000x reference)
//
#include <hip/hip_runtime.h>

#define N_NODES 50000
#define N_EDGES 800000
#define N_HEADS 4
#define HEAD_DIM 32
#define ALPHA 0.2f
#define FEAT 128  // N_HEADS * HEAD_DIM

// One 64-lane wave per edge. Lane t handles elements 2t, 2t+1 of the 128-elem
// per-edge feature vector. Head h = (2t)>>5; 16-lane groups own one head.
__global__ __launch_bounds__(256) void gat_edge_kernel(
    const float* __restrict__ edge_emb,
    const float* __restrict__ node_emb,
    const float* __restrict__ attn_w,
    const int*   __restrict__ src,
    const int*   __restrict__ dst,
    float* __restrict__ out,
    float* __restrict__ seg_sum)
{
    const int wave = threadIdx.x >> 6;   // 4 edges per 256-thread block
    const int lane = threadIdx.x & 63;
    const int e = blockIdx.x * 4 + wave;
    if (e >= N_EDGES) return;

    const int s = __builtin_amdgcn_readfirstlane(src[e]);
    const int d = __builtin_amdgcn_readfirstlane(dst[e]);

    const int i = lane * 2;       // element index 0..126
    const int h = i >> 5;         // head index 0..3

    const float2 xe = *reinterpret_cast<const float2*>(edge_emb + (size_t)e * FEAT + i);
    const float2 w  = *reinterpret_cast<const float2*>(attn_w + i);  // [H,Dh,1] contiguous

    float p = xe.x * w.x + xe.y * w.y;
    // butterfly reduce within each 16-lane group (one head)
    p += __shfl_xor(p, 1);
    p += __shfl_xor(p, 2);
    p += __shfl_xor(p, 4);
    p += __shfl_xor(p, 8);

    const float logit = (p >= 0.f) ? p : ALPHA * p;
    const float ex = __expf(logit);   // no max-subtraction needed (|logit| <~ 8)

    if ((lane & 15) == 0)
        atomicAdd(&seg_sum[d * N_HEADS + h], ex);

    const float2 xn = *reinterpret_cast<const float2*>(node_emb + (size_t)s * FEAT + i);

    atomicAdd(&out[d * FEAT + i],     ex * xe.x * xn.x);
    atomicAdd(&out[d * FEAT + i + 1], ex * xe.y * xn.y);
}

// out[n,h,d] /= seg_sum[n,h]; empty segments stay 0.
__global__ __launch_bounds__(256) void gat_norm_kernel(
    const float* __restrict__ seg_sum,
    float* __restrict__ out)
{
    const int idx = blockIdx.x * blockDim.x + threadIdx.x;  // one float4 each
    if (idx >= N_NODES * (FEAT / 4)) return;
    const int n = idx >> 5;        // 32 float4 per node
    const int q = idx & 31;        // float4 slot within node
    const int h = q >> 3;          // 8 float4 per head
    const float ssum = seg_sum[n * N_HEADS + h];
    const float inv = (ssum > 0.f) ? 1.0f / ssum : 0.f;
    float4 v = reinterpret_cast<float4*>(out)[idx];
    v.x *= inv; v.y *= inv; v.z *= inv; v.w *= inv;
    reinterpret_cast<float4*>(out)[idx] = v;
}

extern "C" void kernel_launch(void* const* d_in, const int* in_sizes, int n_in,
                              void* d_out, int out_size, void* d_ws, size_t ws_size,
                              hipStream_t stream)
{
    const float* edge_emb = (const float*)d_in[0];
    const float* node_emb = (const float*)d_in[1];
    const float* attn_w   = (const float*)d_in[2];
    const int*   src      = (const int*)d_in[3];
    const int*   dst      = (const int*)d_in[4];
    float* out = (float*)d_out;
    float* seg_sum = (float*)d_ws;   // N_NODES * N_HEADS floats = 800 KB

    hipMemsetAsync(out, 0, (size_t)N_NODES * FEAT * sizeof(float), stream);
    hipMemsetAsync(seg_sum, 0, (size_t)N_NODES * N_HEADS * sizeof(float), stream);

    gat_edge_kernel<<<N_EDGES / 4, 256, 0, stream>>>(
        edge_emb, node_emb, attn_w, src, dst, out, seg_sum);

    const int norm_threads = N_NODES * (FEAT / 4);
    gat_norm_kernel<<<(norm_threads + 255) / 256, 256, 0, stream>>>(seg_sum, out);
}